// Round 12
// baseline (73.570 us; speedup 1.0000x reference)
//
#include <hip/hip_runtime.h>
#include <cstdint>
#include <cstddef>

#define B_ 4
#define L_ 2048
#define D_ 512
#define H_ 512
#define CH 64            // scan chunk length (2 chunks per 128-row GEMM m-tile)
#define NC (L_ / CH)     // 32 chunks
#define NS 4             // W_next K-split (K=512 per partial)

typedef unsigned short u16;
typedef __attribute__((ext_vector_type(8))) short short8v;   // 8 bf16 (4 VGPRs)
typedef __attribute__((ext_vector_type(4))) float f32x4;

typedef __attribute__((address_space(3))) unsigned lds_uint;
typedef const __attribute__((address_space(1))) unsigned glob_uint;

__device__ __forceinline__ void glds16(const u16* g, const u16* l) {
    __builtin_amdgcn_global_load_lds((glob_uint*)g, (lds_uint*)l, 16, 0, 0);
}

// ---------- bf16 helpers ----------
__device__ __forceinline__ u16 bf16_rne(float x) {
    union { float f; unsigned u; } v; v.f = x;
    unsigned r = v.u + 0x7fffu + ((v.u >> 16) & 1u);
    return (u16)(r >> 16);
}
__device__ __forceinline__ float bf16_tof(u16 h) {
    union { unsigned u; float f; } v; v.u = ((unsigned)h) << 16;
    return v.f;
}

// ---------------- K1: rowscalars + x->bf16 ----------------
// LESSONS: r10 threadfence ~250us; r14 bulk atomics +10us; r13/r15 <2waves/SIMD
// regress; r16 carry recompute +4.4us; r17 PROBE: C0~=10.7us fixed; r18 store-
// coalescing neutral; r19 8-wave WIN; r20 BK=64 WIN; r21 3-buf/1-barrier qk+wn WIN
// (69.6). ROUND-22: ev's dual-AB converts to 3-buf/1-barrier by reading B1=Wvh
// (512KB, shared by all blocks, L2-resident) directly into VGPRs — LDS stages only
// A0/A1/B0 (147456B). vmcnt order: barrier -> B1 frag loads -> stage(t+2) so the
// compiler's B1 wait is vmcnt(6) and the glds pipeline stays counted.
__global__ __launch_bounds__(256) void k_prep(
    const float* __restrict__ x, const float* __restrict__ flr_w, const float* __restrict__ flr_b,
    const float* __restrict__ fwd_w, const float* __restrict__ fwd_b,
    const float* __restrict__ lblr, const float* __restrict__ lbwd,
    float* __restrict__ lr, float* __restrict__ lwd, float* __restrict__ wd,
    u16* __restrict__ xh)
{
    int bx = blockIdx.x;
    int wave = threadIdx.x >> 6;
    int lane = threadIdx.x & 63;
    int row  = bx * 4 + wave;                          // [0, B*L)
    const float4* xr = (const float4*)(x + (size_t)row * D_);
    const float4* wl = (const float4*)flr_w;
    const float4* ww = (const float4*)fwd_w;
    float zl = 0.f, zw = 0.f;
#pragma unroll
    for (int i = 0; i < 2; ++i) {
        int idx = lane + i * 64;
        float4 xv = xr[idx];
        float4 av = wl[idx];
        float4 bv = ww[idx];
        zl += xv.x*av.x + xv.y*av.y + xv.z*av.z + xv.w*av.w;
        zw += xv.x*bv.x + xv.y*bv.y + xv.z*bv.z + xv.w*bv.w;
        ushort4 h4;
        h4.x = bf16_rne(xv.x); h4.y = bf16_rne(xv.y);
        h4.z = bf16_rne(xv.z); h4.w = bf16_rne(xv.w);
        *(ushort4*)(xh + (size_t)row * D_ + idx * 4) = h4;
    }
#pragma unroll
    for (int off = 32; off; off >>= 1) {
        zl += __shfl_xor(zl, off, 64);
        zw += __shfl_xor(zw, off, 64);
    }
    if (lane == 0) {
        zl += flr_b[0];
        zw += fwd_b[0];
        float lrv = expf(lblr[0]) / (1.f + expf(-zl));
        float ls = (zw >= 0.f) ? (-log1pf(expf(-zw))) : (zw - log1pf(expf(zw)));  // log sigmoid
        float lw = lbwd[0] + ls;
        lr[row]  = lrv;
        lwd[row] = lw;
        wd[row]  = expf(lw);
    }
}

// ---------------- K2: per-batch prefix scan (4 blocks) + weight->bf16 (1792 blocks) ----------------
__global__ __launch_bounds__(256) void k_cumsum(
    const float* __restrict__ lwd, const float* __restrict__ lr,
    const float* __restrict__ Wq, const float* __restrict__ Wk, const float* __restrict__ Wv,
    const float* __restrict__ hid,
    u16* __restrict__ Wqh, u16* __restrict__ Wkh, u16* __restrict__ Wvh, u16* __restrict__ Wph,
    float* __restrict__ cum, float* __restrict__ wdc, float* __restrict__ c)
{
    int bx = blockIdx.x;
    if (bx >= B_) {
        int idx = bx - B_;
        int y = idx >> 8;
        const size_t DH = (size_t)D_ * H_;
        const float* s; u16* d;
        if      (y == 0) { s = Wq; d = Wqh; }
        else if (y == 1) { s = Wk; d = Wkh; }
        else if (y == 2) { s = Wv; d = Wvh; }
        else             { s = hid + (size_t)(y - 3) * DH; d = Wph + (size_t)(y - 3) * DH; }
        int i = ((idx & 255) * 256 + threadIdx.x) * 4;
        float4 v = *(const float4*)(s + i);
        ushort4 h4;
        h4.x = bf16_rne(v.x); h4.y = bf16_rne(v.y);
        h4.z = bf16_rne(v.z); h4.w = bf16_rne(v.w);
        *(ushort4*)(d + i) = h4;
        return;
    }
    int b = bx;
    int t = threadIdx.x;
    const float* in = lwd + (size_t)b * L_;
    float v[8];
    float s = 0.f;
#pragma unroll
    for (int j = 0; j < 8; ++j) { s += in[t*8 + j]; v[j] = s; }
    __shared__ float sd[256];
    __shared__ float totb;
    sd[t] = s;
    __syncthreads();
    for (int d = 1; d < 256; d <<= 1) {
        float xv = (t >= d) ? sd[t - d] : 0.f;
        __syncthreads();
        sd[t] += xv;
        __syncthreads();
    }
    float excl = sd[t] - s;
    if (t == 255) totb = sd[255];
    __syncthreads();
    float total = totb;
#pragma unroll
    for (int j = 0; j < 8; ++j) {
        int l = t*8 + j;
        float cv = excl + v[j];
        cum[(size_t)b*L_ + l] = cv;
        wdc[(size_t)b*L_ + l] = expf(cv);
        c[(size_t)b*L_ + l]   = lr[(size_t)b*L_ + l] * expf(total - cv);
    }
}

// ======= 8-wave 128x128 GEMM cores, BK=64 (512 thr, wave grid 2x4, 64x32/wave/plane) =======
// Staging: r=tid>>3, slot=tid&7 (8x16B slots/row, row stride 128B), swizzle
// slot^=(row>>1)&7 pre-applied on SOURCE (linear glds dest) and on read.
// All cores: 3-buffer rotation, ONE barrier per K-step.

__device__ __forceinline__ void gg64(int lda, int ldb, int m0, int n0,
                                     size_t& gA, size_t& gB, int& dst,
                                     int offA[2][4], int offB[2][2]) {
    const int tid = threadIdx.x;
    const int lane = tid & 63;
    const int wv = tid >> 6, wm = wv >> 2, wn = wv & 3;
    int r = tid >> 3, s = tid & 7;
    int sg = s ^ ((r >> 1) & 7);
    gA = (size_t)(m0 + r) * lda + sg * 8;
    gB = (size_t)(n0 + r) * ldb + sg * 8;
    dst = wv * 1024;                      // linear: byte = tid*16; half2 dest = +8192
#pragma unroll
    for (int ks = 0; ks < 2; ++ks) {
#pragma unroll
        for (int f = 0; f < 4; ++f) {
            int ra = wm * 64 + f * 16 + (lane & 15);
            offA[ks][f] = ra * 128 + (((ks * 4 + (lane >> 4)) ^ ((ra >> 1) & 7)) * 16);
        }
#pragma unroll
        for (int f = 0; f < 2; ++f) {
            int rb = wn * 32 + f * 16 + (lane & 15);
            offB[ks][f] = rb * 128 + (((ks * 4 + (lane >> 4)) ^ ((rb >> 1) & 7)) * 16);
        }
    }
}

// ---- dual-B (3-buf/1-barrier): acc0 = A.B0^T, acc1 = A.B1^T.
// smem: A 3x16K @0; B0 3x16K @49152; B1 3x16K @98304 (147456 total)
__device__ __forceinline__ void core8_dualB(
    char* smem, const u16* __restrict__ A_g,
    const u16* __restrict__ B0_g, const u16* __restrict__ B1_g,
    int lda, int ldb, int K, int m0, int n0, f32x4 acc0[4][2], f32x4 acc1[4][2])
{
    size_t gA, gB; int dst; int offA[2][4], offB[2][2];
    gg64(lda, ldb, m0, n0, gA, gB, dst, offA, offB);
    const size_t hA = (size_t)64 * lda, hB = (size_t)64 * ldb;
    auto stage = [&](int bi, int k0) {
        glds16(A_g  + gA + k0,      (const u16*)(smem + bi * 16384 + dst));
        glds16(A_g  + gA + hA + k0, (const u16*)(smem + bi * 16384 + 8192 + dst));
        glds16(B0_g + gB + k0,      (const u16*)(smem + 49152 + bi * 16384 + dst));
        glds16(B0_g + gB + hB + k0, (const u16*)(smem + 49152 + bi * 16384 + 8192 + dst));
        glds16(B1_g + gB + k0,      (const u16*)(smem + 98304 + bi * 16384 + dst));
        glds16(B1_g + gB + hB + k0, (const u16*)(smem + 98304 + bi * 16384 + 8192 + dst));
    };
    const int nt = K >> 6;
    stage(0, 0);
    if (nt > 1) stage(1, 64);
    int bi = 0, bs = 2;
    for (int t = 0; t < nt; ++t) {
        if (t + 1 < nt) asm volatile("s_waitcnt vmcnt(6)" ::: "memory");
        else            asm volatile("s_waitcnt vmcnt(0)" ::: "memory");
        __builtin_amdgcn_s_barrier();
        asm volatile("" ::: "memory");
        if (t + 2 < nt) stage(bs, (t + 2) << 6);
        const char* bA  = smem + bi * 16384;
        const char* bB0 = smem + 49152 + bi * 16384;
        const char* bB1 = smem + 98304 + bi * 16384;
#pragma unroll
        for (int ks = 0; ks < 2; ++ks) {
            short8v a0 = *(const short8v*)(bA + offA[ks][0]);
            short8v a1 = *(const short8v*)(bA + offA[ks][1]);
            short8v a2 = *(const short8v*)(bA + offA[ks][2]);
            short8v a3 = *(const short8v*)(bA + offA[ks][3]);
            short8v p0 = *(const short8v*)(bB0 + offB[ks][0]);
            short8v p1 = *(const short8v*)(bB0 + offB[ks][1]);
            short8v q0 = *(const short8v*)(bB1 + offB[ks][0]);
            short8v q1 = *(const short8v*)(bB1 + offB[ks][1]);
            __builtin_amdgcn_s_setprio(1);
            acc0[0][0] = __builtin_amdgcn_mfma_f32_16x16x32_bf16(a0, p0, acc0[0][0], 0, 0, 0);
            acc0[0][1] = __builtin_amdgcn_mfma_f32_16x16x32_bf16(a0, p1, acc0[0][1], 0, 0, 0);
            acc0[1][0] = __builtin_amdgcn_mfma_f32_16x16x32_bf16(a1, p0, acc0[1][0], 0, 0, 0);
            acc0[1][1] = __builtin_amdgcn_mfma_f32_16x16x32_bf16(a1, p1, acc0[1][1], 0, 0, 0);
            acc0[2][0] = __builtin_amdgcn_mfma_f32_16x16x32_bf16(a2, p0, acc0[2][0], 0, 0, 0);
            acc0[2][1] = __builtin_amdgcn_mfma_f32_16x16x32_bf16(a2, p1, acc0[2][1], 0, 0, 0);
            acc0[3][0] = __builtin_amdgcn_mfma_f32_16x16x32_bf16(a3, p0, acc0[3][0], 0, 0, 0);
            acc0[3][1] = __builtin_amdgcn_mfma_f32_16x16x32_bf16(a3, p1, acc0[3][1], 0, 0, 0);
            acc1[0][0] = __builtin_amdgcn_mfma_f32_16x16x32_bf16(a0, q0, acc1[0][0], 0, 0, 0);
            acc1[0][1] = __builtin_amdgcn_mfma_f32_16x16x32_bf16(a0, q1, acc1[0][1], 0, 0, 0);
            acc1[1][0] = __builtin_amdgcn_mfma_f32_16x16x32_bf16(a1, q0, acc1[1][0], 0, 0, 0);
            acc1[1][1] = __builtin_amdgcn_mfma_f32_16x16x32_bf16(a1, q1, acc1[1][1], 0, 0, 0);
            acc1[2][0] = __builtin_amdgcn_mfma_f32_16x16x32_bf16(a2, q0, acc1[2][0], 0, 0, 0);
            acc1[2][1] = __builtin_amdgcn_mfma_f32_16x16x32_bf16(a2, q1, acc1[2][1], 0, 0, 0);
            acc1[3][0] = __builtin_amdgcn_mfma_f32_16x16x32_bf16(a3, q0, acc1[3][0], 0, 0, 0);
            acc1[3][1] = __builtin_amdgcn_mfma_f32_16x16x32_bf16(a3, q1, acc1[3][1], 0, 0, 0);
            __builtin_amdgcn_s_setprio(0);
        }
        asm volatile("" ::: "memory");
        bi = (bi == 2) ? 0 : bi + 1;
        bs = (bs == 2) ? 0 : bs + 1;
    }
    asm volatile("" ::: "memory");
    __builtin_amdgcn_s_barrier();            // protect epilogue smem reuse
}

// ---- dual-AB, B1 from L2 (3-buf/1-barrier): acc0 = A0.B0^T, acc1 = A1.B1^T.
// smem: A0 3x16K @0; A1 3x16K @49152; B0 3x16K @98304 (147456). B1 fragments are
// loaded straight from global (L2-resident Wvh) into VGPRs each step, AFTER the
// barrier and BEFORE stage(t+2) so the compiler's wait for them is vmcnt(6).
__device__ __forceinline__ void core8_dualAB_bl2(
    char* smem, const u16* __restrict__ A0_g, const u16* __restrict__ A1_g,
    const u16* __restrict__ B0_g, const u16* __restrict__ B1_g,
    int lda, int ldb, int K, int m0, int n0, f32x4 acc0[4][2], f32x4 acc1[4][2])
{
    size_t gA, gB; int dst; int offA[2][4], offB[2][2];
    gg64(lda, ldb, m0, n0, gA, gB, dst, offA, offB);
    const int lane = threadIdx.x & 63;
    const int wn = (threadIdx.x >> 6) & 3;
    const u16* b1p[2][2];
#pragma unroll
    for (int ks = 0; ks < 2; ++ks)
#pragma unroll
        for (int f = 0; f < 2; ++f)
            b1p[ks][f] = B1_g + (size_t)(n0 + wn*32 + f*16 + (lane & 15)) * ldb
                              + (ks * 4 + (lane >> 4)) * 8;
    const size_t hA = (size_t)64 * lda, hB = (size_t)64 * ldb;
    auto stage = [&](int bi, int k0) {
        glds16(A0_g + gA + k0,      (const u16*)(smem + bi * 16384 + dst));
        glds16(A0_g + gA + hA + k0, (const u16*)(smem + bi * 16384 + 8192 + dst));
        glds16(A1_g + gA + k0,      (const u16*)(smem + 49152 + bi * 16384 + dst));
        glds16(A1_g + gA + hA + k0, (const u16*)(smem + 49152 + bi * 16384 + 8192 + dst));
        glds16(B0_g + gB + k0,      (const u16*)(smem + 98304 + bi * 16384 + dst));
        glds16(B0_g + gB + hB + k0, (const u16*)(smem + 98304 + bi * 16384 + 8192 + dst));
    };
    const int nt = K >> 6;
    stage(0, 0);
    if (nt > 1) stage(1, 64);
    int bi = 0, bs = 2;
    for (int t = 0; t < nt; ++t) {
        if (t + 1 < nt) asm volatile("s_waitcnt vmcnt(6)" ::: "memory");
        else            asm volatile("s_waitcnt vmcnt(0)" ::: "memory");
        __builtin_amdgcn_s_barrier();
        asm volatile("" ::: "memory");
        const int kcur = t << 6;
        short8v q00 = *(const short8v*)(b1p[0][0] + kcur);
        short8v q01 = *(const short8v*)(b1p[0][1] + kcur);
        short8v q10 = *(const short8v*)(b1p[1][0] + kcur);
        short8v q11 = *(const short8v*)(b1p[1][1] + kcur);
        if (t + 2 < nt) stage(bs, (t + 2) << 6);
        const char* bA0 = smem + bi * 16384;
        const char* bA1 = smem + 49152 + bi * 16384;
        const char* bB0 = smem + 98304 + bi * 16384;
#pragma unroll
        for (int ks = 0; ks < 2; ++ks) {
            short8v a0 = *(const short8v*)(bA0 + offA[ks][0]);
            short8v a1 = *(const short8v*)(bA0 + offA[ks][1]);
            short8v a2 = *(const short8v*)(bA0 + offA[ks][2]);
            short8v a3 = *(const short8v*)(bA0 + offA[ks][3]);
            short8v c0 = *(const short8v*)(bA1 + offA[ks][0]);
            short8v c1 = *(const short8v*)(bA1 + offA[ks][1]);
            short8v c2 = *(const short8v*)(bA1 + offA[ks][2]);
            short8v c3 = *(const short8v*)(bA1 + offA[ks][3]);
            short8v p0 = *(const short8v*)(bB0 + offB[ks][0]);
            short8v p1 = *(const short8v*)(bB0 + offB[ks][1]);
            short8v q0 = ks ? q10 : q00;
            short8v q1 = ks ? q11 : q01;
            __builtin_amdgcn_s_setprio(1);
            acc0[0][0] = __builtin_amdgcn_mfma_f32_16x16x32_bf16(a0, p0, acc0[0][0], 0, 0, 0);
            acc0[0][1] = __builtin_amdgcn_mfma_f32_16x16x32_bf16(a0, p1, acc0[0][1], 0, 0, 0);
            acc0[1][0] = __builtin_amdgcn_mfma_f32_16x16x32_bf16(a1, p0, acc0[1][0], 0, 0, 0);
            acc0[1][1] = __builtin_amdgcn_mfma_f32_16x16x32_bf16(a1, p1, acc0[1][1], 0, 0, 0);
            acc0[2][0] = __builtin_amdgcn_mfma_f32_16x16x32_bf16(a2, p0, acc0[2][0], 0, 0, 0);
            acc0[2][1] = __builtin_amdgcn_mfma_f32_16x16x32_bf16(a2, p1, acc0[2][1], 0, 0, 0);
            acc0[3][0] = __builtin_amdgcn_mfma_f32_16x16x32_bf16(a3, p0, acc0[3][0], 0, 0, 0);
            acc0[3][1] = __builtin_amdgcn_mfma_f32_16x16x32_bf16(a3, p1, acc0[3][1], 0, 0, 0);
            acc1[0][0] = __builtin_amdgcn_mfma_f32_16x16x32_bf16(c0, q0, acc1[0][0], 0, 0, 0);
            acc1[0][1] = __builtin_amdgcn_mfma_f32_16x16x32_bf16(c0, q1, acc1[0][1], 0, 0, 0);
            acc1[1][0] = __builtin_amdgcn_mfma_f32_16x16x32_bf16(c1, q0, acc1[1][0], 0, 0, 0);
            acc1[1][1] = __builtin_amdgcn_mfma_f32_16x16x32_bf16(c1, q1, acc1[1][1], 0, 0, 0);
            acc1[2][0] = __builtin_amdgcn_mfma_f32_16x16x32_bf16(c2, q0, acc1[2][0], 0, 0, 0);
            acc1[2][1] = __builtin_amdgcn_mfma_f32_16x16x32_bf16(c2, q1, acc1[2][1], 0, 0, 0);
            acc1[3][0] = __builtin_amdgcn_mfma_f32_16x16x32_bf16(c3, q0, acc1[3][0], 0, 0, 0);
            acc1[3][1] = __builtin_amdgcn_mfma_f32_16x16x32_bf16(c3, q1, acc1[3][1], 0, 0, 0);
            __builtin_amdgcn_s_setprio(0);
        }
        asm volatile("" ::: "memory");
        bi = (bi == 2) ? 0 : bi + 1;
        bs = (bs == 2) ? 0 : bs + 1;
    }
}

// ---- single (3-buf/1-barrier): smem A 3x16K @0; B 3x16K @49152 (98304)
__device__ __forceinline__ void core8_single(
    char* smem, const u16* __restrict__ A_g, const u16* __restrict__ B_g,
    int lda, int ldb, int K, int m0, int n0, f32x4 acc[4][2])
{
    size_t gA, gB; int dst; int offA[2][4], offB[2][2];
    gg64(lda, ldb, m0, n0, gA, gB, dst, offA, offB);
    const size_t hA = (size_t)64 * lda, hB = (size_t)64 * ldb;
    auto stage = [&](int bi, int k0) {
        glds16(A_g + gA + k0,      (const u16*)(smem + bi * 16384 + dst));
        glds16(A_g + gA + hA + k0, (const u16*)(smem + bi * 16384 + 8192 + dst));
        glds16(B_g + gB + k0,      (const u16*)(smem + 49152 + bi * 16384 + dst));
        glds16(B_g + gB + hB + k0, (const u16*)(smem + 49152 + bi * 16384 + 8192 + dst));
    };
    const int nt = K >> 6;
    stage(0, 0);
    if (nt > 1) stage(1, 64);
    int bi = 0, bs = 2;
    for (int t = 0; t < nt; ++t) {
        if (t + 1 < nt) asm volatile("s_waitcnt vmcnt(4)" ::: "memory");
        else            asm volatile("s_waitcnt vmcnt(0)" ::: "memory");
        __builtin_amdgcn_s_barrier();
        asm volatile("" ::: "memory");
        if (t + 2 < nt) stage(bs, (t + 2) << 6);
        const char* bA = smem + bi * 16384;
        const char* bB = smem + 49152 + bi * 16384;
#pragma unroll
        for (int ks = 0; ks < 2; ++ks) {
            short8v a0 = *(const short8v*)(bA + offA[ks][0]);
            short8v a1 = *(const short8v*)(bA + offA[ks][1]);
            short8v a2 = *(const short8v*)(bA + offA[ks][2]);
            short8v a3 = *(const short8v*)(bA + offA[ks][3]);
            short8v p0 = *(const short8v*)(bB + offB[ks][0]);
            short8v p1 = *(const short8v*)(bB + offB[ks][1]);
            __builtin_amdgcn_s_setprio(1);
            acc[0][0] = __builtin_amdgcn_mfma_f32_16x16x32_bf16(a0, p0, acc[0][0], 0, 0, 0);
            acc[0][1] = __builtin_amdgcn_mfma_f32_16x16x32_bf16(a0, p1, acc[0][1], 0, 0, 0);
            acc[1][0] = __builtin_amdgcn_mfma_f32_16x16x32_bf16(a1, p0, acc[1][0], 0, 0, 0);
            acc[1][1] = __builtin_amdgcn_mfma_f32_16x16x32_bf16(a1, p1, acc[1][1], 0, 0, 0);
            acc[2][0] = __builtin_amdgcn_mfma_f32_16x16x32_bf16(a2, p0, acc[2][0], 0, 0, 0);
            acc[2][1] = __builtin_amdgcn_mfma_f32_16x16x32_bf16(a2, p1, acc[2][1], 0, 0, 0);
            acc[3][0] = __builtin_amdgcn_mfma_f32_16x16x32_bf16(a3, p0, acc[3][0], 0, 0, 0);
            acc[3][1] = __builtin_amdgcn_mfma_f32_16x16x32_bf16(a3, p1, acc[3][1], 0, 0, 0);
            __builtin_amdgcn_s_setprio(0);
        }
        asm volatile("" ::: "memory");
        bi = (bi == 2) ? 0 : bi + 1;
        bs = (bs == 2) ? 0 : bs + 1;
    }
    asm volatile("" ::: "memory");
    __builtin_amdgcn_s_barrier();
}

// ---------------- K3: q+k dual GEMM; scan->Gloc from q-acc; kh + (c*k)^T from k-acc ----------------
__global__ __launch_bounds__(512) void k_mfma_qk(
    const u16* __restrict__ xh,
    const u16* __restrict__ Wqh, const u16* __restrict__ Wkh,
    const float* __restrict__ cvec, const float* __restrict__ wd,
    u16* __restrict__ kh, u16* __restrict__ kcth, u16* __restrict__ Gloc)
{
    __shared__ __align__(16) char smem[147456];  // core 144K; scan reuses 32K
    __shared__ float pwd[128];
    int flat = blockIdx.x;
    flat = (flat & 7) * 32 + (flat >> 3);        // bijective XCD swizzle (nwg=256)
    int n0 = (flat & 3) * 128;
    int m0 = (flat >> 2) * 128;
    f32x4 accq[4][2], acck[4][2];
#pragma unroll
    for (int i = 0; i < 4; ++i)
#pragma unroll
    for (int j = 0; j < 2; ++j) { accq[i][j] = 0.f; acck[i][j] = 0.f; }
    core8_dualB(smem, xh, Wqh, Wkh, D_, D_, D_, m0, n0, accq, acck);

    const int lane = threadIdx.x & 63;
    const int wv = threadIdx.x >> 6, wm = wv >> 2, wn = wv & 3;
    const int colq = lane & 15, rq = lane >> 4;

    // ---- k epilogue (global only) ----
#pragma unroll
    for (int mf = 0; mf < 4; ++mf) {
        int grow0 = m0 + wm*64 + mf*16 + rq*4;
        float cv[4];
#pragma unroll
        for (int r = 0; r < 4; ++r) cv[r] = cvec[grow0 + r];
#pragma unroll
        for (int nf = 0; nf < 2; ++nf) {
            int gc = n0 + wn*32 + nf*16 + colq;
            f32x4 a = acck[mf][nf];
            ushort4 hc;
#pragma unroll
            for (int r = 0; r < 4; ++r) {
                kh[(size_t)(grow0 + r) * H_ + gc] = bf16_rne(a[r]);
                ((u16*)&hc)[r] = bf16_rne(cv[r] * a[r]);
            }
            int b = grow0 >> 11, lloc = grow0 & 2047;
            size_t tbase = (size_t)b * (H_ * L_) + (size_t)gc * L_ + lloc;
            *(ushort4*)(kcth + tbase) = hc;
        }
    }

    // ---- fused suffix scan on q-acc (2 chunks of 64 rows; tile = 128 rows) ----
    u16* g = (u16*)smem;                 // [128][128] bf16 = 32KB
#pragma unroll
    for (int mf = 0; mf < 4; ++mf) {
        int rl0 = wm*64 + mf*16 + rq*4;
#pragma unroll
        for (int nf = 0; nf < 2; ++nf) {
            int cl = wn*32 + nf*16 + colq;
#pragma unroll
            for (int r = 0; r < 4; ++r)
                g[(rl0 + r)*128 + cl] = bf16_rne(accq[mf][nf][r]);
        }
    }
    if (threadIdx.x < 128) pwd[threadIdx.x] = wd[m0 + threadIdx.x];
    __syncthreads();
    if (threadIdx.x < 256) {
        int col  = threadIdx.x & 127;
        int base = (threadIdx.x >> 7) * 64;          // chunk 0 or 1
        float G = bf16_tof(g[(base + 63)*128 + col]);
        for (int l = 62; l >= 0; --l) {
            float qv = bf16_tof(g[(base + l)*128 + col]);
            G = fmaf(pwd[base + l + 1], G, qv);
            g[(base + l)*128 + col] = bf16_rne(G);
        }
    }
    __syncthreads();
    int row = threadIdx.x >> 2, c0 = (threadIdx.x & 3) * 32;
    u16* dst = Gloc + (size_t)(m0 + row) * H_ + n0 + c0;
#pragma unroll
    for (int j = 0; j < 4; ++j)
        *(int4*)(dst + j*8) = *(const int4*)&g[row*128 + c0 + j*8];
}

// ---------------- K4: carry across NC chunks: 32 blocks, register chain ----------------
__global__ __launch_bounds__(64) void k_scan_carry(
    const float* __restrict__ cum, const u16* __restrict__ Gloc, float* __restrict__ Gs)
{
    int b = blockIdx.x;
    int h = blockIdx.y * 64 + threadIdx.x;
    __shared__ float dec[NC];
    const float* cb = cum + (size_t)b * L_;
    if (threadIdx.x < NC - 1) dec[threadIdx.x] = expf(cb[(threadIdx.x + 1) * CH] - cb[threadIdx.x * CH]);
    __syncthreads();
    const u16* g = Gloc + (size_t)b * L_ * H_ + h;
    float* gs = Gs + (size_t)b * NC * H_ + h;
    float v[NC];
#pragma unroll
    for (int c = 0; c < NC; ++c)                 // 32 independent loads in flight
        v[c] = bf16_tof(g[(size_t)(c * CH) * H_]);
    float G = v[NC - 1];
    gs[(size_t)(NC - 1) * H_] = G;
#pragma unroll
    for (int c = NC - 2; c >= 0; --c) {
        G = fmaf(dec[c], G, v[c]);
        gs[(size_t)c * H_] = G;
    }
}

// ---------------- K5: fused apply+dot: S[row] = k . (Gloc + a*Gs[c+1]) ----------------
__global__ __launch_bounds__(256) void k_sdot(
    const u16* __restrict__ kh,
    const u16* __restrict__ Gloc, const float* __restrict__ Gs,
    const float* __restrict__ cum, float* __restrict__ S)
{
    int wave = threadIdx.x >> 6, lane = threadIdx.x & 63;
    int row = blockIdx.x * 4 + wave;                 // b*L + l
    int b = row >> 11, l = row & 2047;
    int c = l / CH;
    float a = 0.f;
    const float* gsr = Gs;                           // dummy, masked by a=0
    if (c < NC - 1) {
        a = expf(cum[((size_t)b << 11) + (size_t)((c + 1) * CH)] - cum[row]);
        gsr = Gs + ((size_t)(b * NC + c + 1)) * H_;
    }
    const u16* khr = kh + (size_t)row * H_;
    const u16* glr = Gloc + (size_t)row * H_;
    const float4* gq = (const float4*)gsr;
    float s = 0.f;
    int base = lane * 8;
    ushort4 h0 = *(const ushort4*)(khr + base);
    ushort4 h1 = *(const ushort4*)(khr + base + 4);
    ushort4 g0 = *(const ushort4*)(glr + base);
    ushort4 g1 = *(const ushort4*)(glr + base + 4);
    float4 s0 = gq[lane * 2];
    float4 s1 = gq[lane * 2 + 1];
    s += bf16_tof(h0.x) * fmaf(a, s0.x, bf16_tof(g0.x));
    s += bf16_tof(h0.y) * fmaf(a, s0.y, bf16_tof(g0.y));
    s += bf16_tof(h0.z) * fmaf(a, s0.z, bf16_tof(g0.z));
    s += bf16_tof(h0.w) * fmaf(a, s0.w, bf16_tof(g0.w));
    s += bf16_tof(h1.x) * fmaf(a, s1.x, bf16_tof(g1.x));
    s += bf16_tof(h1.y) * fmaf(a, s1.y, bf16_tof(g1.y));
    s += bf16_tof(h1.z) * fmaf(a, s1.z, bf16_tof(g1.z));
    s += bf16_tof(h1.w) * fmaf(a, s1.w, bf16_tof(g1.w));
#pragma unroll
    for (int off = 32; off; off >>= 1) s += __shfl_xor(s, off, 64);
    if (lane == 0) S[row] = s;
}

// ---------------- K6: E+v dual GEMM; y + E^T epilogue (v never materialized) ----------------
__global__ __launch_bounds__(512) void k_mfma_ev(
    const u16* __restrict__ kh, const u16* __restrict__ xh,
    const u16* __restrict__ Wph, const u16* __restrict__ Wvh,
    const float* __restrict__ lr, const float* __restrict__ S, const float* __restrict__ wdc,
    float* __restrict__ y, u16* __restrict__ Eth)
{
    __shared__ __align__(16) char smem[147456];
    int flat = blockIdx.x;
    flat = (flat & 7) * 32 + (flat >> 3);        // nwg=256
    int n0 = (flat & 3) * 128;
    int m0 = ((flat >> 2) & 15) * 128;
    int b  = flat >> 6;
    f32x4 acce[4][2], accv[4][2];
#pragma unroll
    for (int i = 0; i < 4; ++i)
#pragma unroll
    for (int j = 0; j < 2; ++j) { acce[i][j] = 0.f; accv[i][j] = 0.f; }
    core8_dualAB_bl2(smem, kh + (size_t)b * L_ * H_, xh + (size_t)b * L_ * D_,
                     Wph + (size_t)b * D_ * H_, Wvh,
                     H_, H_, H_, m0, n0, acce, accv);

    const int lane = threadIdx.x & 63;
    const int wv = threadIdx.x >> 6, wm = wv >> 2, wn = wv & 3;
    const int colq = lane & 15, rq = lane >> 4;
#pragma unroll
    for (int mf = 0; mf < 4; ++mf) {
        int grow0 = m0 + wm*64 + mf*16 + rq*4;       // local l
        float ayv[4], wdv[4];
#pragma unroll
        for (int r = 0; r < 4; ++r) {
            size_t grow = (size_t)b * L_ + grow0 + r;
            ayv[r] = -lr[grow] * S[grow];
            wdv[r] = wdc[grow];
        }
#pragma unroll
        for (int nf = 0; nf < 2; ++nf) {
            int gc = n0 + wn*32 + nf*16 + colq;      // d
            f32x4 ae = acce[mf][nf];
            f32x4 av = accv[mf][nf];
            ushort4 he;
#pragma unroll
            for (int r = 0; r < 4; ++r) {
                size_t gi = ((size_t)b * L_ + grow0 + r) * D_ + gc;
                float e = ae[r] - av[r];               // E = k.Wp^T - v
                y[gi] = e * ayv[r] + ae[r] * wdv[r];   // y = E*(-lr*S) + (E+v)*wd_cross
                ((u16*)&he)[r] = bf16_rne(e);
            }
            size_t tbase = (size_t)b * (D_ * L_) + (size_t)gc * L_ + grow0;
            *(ushort4*)(Eth + tbase) = he;
        }
    }
}

// ---------------- K7: W_next inner partials via MFMA (NS-way K-split, bf16 out) ----------------
__global__ __launch_bounds__(512) void k_mfma_wn(
    const u16* __restrict__ Eth, const u16* __restrict__ kcth,
    u16* __restrict__ wp)
{
    __shared__ __align__(16) char smem[98304];
    int flat = blockIdx.x;
    flat = (flat & 7) * 32 + (flat >> 3);        // bijective XCD swizzle (nwg=256)
    int n0 = (flat & 3) * 128;
    int m0 = ((flat >> 2) & 3) * 128;
    int z  = flat >> 4;                           // [0,16)
    int b = z >> 2, s = z & 3;
    f32x4 acc[4][2];
#pragma unroll
    for (int i = 0; i < 4; ++i)
#pragma unroll
    for (int j = 0; j < 2; ++j) acc[i][j] = 0.f;
    const size_t pa = (size_t)b * (D_ * L_) + (size_t)s * (L_ / NS);
    const size_t pb = (size_t)b * (H_ * L_) + (size_t)s * (L_ / NS);
    core8_single(smem, Eth + pa, kcth + pb, L_, L_, L_ / NS, m0, n0, acc);

    u16* out = wp + (size_t)z * D_ * H_;
    const int lane = threadIdx.x & 63;
    const int wv = threadIdx.x >> 6, wm = wv >> 2, wn = wv & 3;
    const int colq = lane & 15, rq = lane >> 4;
#pragma unroll
    for (int mf = 0; mf < 4; ++mf) {
        int grow0 = m0 + wm*64 + mf*16 + rq*4;
#pragma unroll
        for (int nf = 0; nf < 2; ++nf) {
            int gc = n0 + wn*32 + nf*16 + colq;
            f32x4 a = acc[mf][nf];
#pragma unroll
            for (int r = 0; r < 4; ++r) out[(size_t)(grow0 + r) * H_ + gc] = bf16_rne(a[r]);
        }
    }
}

// ---------------- K8: W_next = wdc[L-1]*W_prev - sum_s bf16 partial ----------------
__global__ __launch_bounds__(256) void k_wnext_reduce(
    const float* __restrict__ Wp, const u16* __restrict__ wp, const float* __restrict__ wdc,
    float* __restrict__ outw)
{
    size_t g = (size_t)blockIdx.x * 256 + threadIdx.x;   // float4 over B*D*H/4
    size_t per = (size_t)D_ * H_ / 4;
    int b = (int)(g / per);
    size_t r = g % per;
    float wl = wdc[(size_t)b * L_ + (L_ - 1)];
    float4 w0 = ((const float4*)Wp)[g];
    float4 o;
    o.x = wl * w0.x; o.y = wl * w0.y; o.z = wl * w0.z; o.w = wl * w0.w;
#pragma unroll
    for (int s = 0; s < NS; ++s) {
        ushort4 p = ((const ushort4*)wp)[(size_t)(b * NS + s) * per + r];
        o.x -= bf16_tof(p.x); o.y -= bf16_tof(p.y);
        o.z -= bf16_tof(p.z); o.w -= bf16_tof(p.w);
    }
    ((float4*)outw)[g] = o;
}

extern "C" void kernel_launch(void* const* d_in, const int* in_sizes, int n_in,
                              void* d_out, int out_size, void* d_ws, size_t ws_size,
                              hipStream_t stream)
{
    (void)in_sizes; (void)n_in; (void)out_size; (void)ws_size;
    const float* x    = (const float*)d_in[0];
    const float* hid  = (const float*)d_in[1];
    const float* lblr = (const float*)d_in[2];
    const float* lbwd = (const float*)d_in[3];
    const float* Wq   = (const float*)d_in[4];
    const float* Wk   = (const float*)d_in[5];
    const float* Wv   = (const float*)d_in[6];
    const float* flrw = (const float*)d_in[7];
    const float* flrb = (const float*)d_in[8];
    const float* fwdw = (const float*)d_in[9];
    const float* fwdb = (const float*)d_in[10];
    float* out = (float*)d_out;

    const size_t BL  = (size_t)B_ * L_;        // 8192
    const size_t BLH = BL * H_;                // 4,194,304
    const size_t DH  = (size_t)D_ * H_;        // 262,144

    char* w = (char*)d_ws;
    u16* Gloc_  = (u16*)w;   w += BLH * 2;        // 8MB  (wp alias start)
    u16* xh_    = (u16*)w;   w += BLH * 2;        // 8MB  (wp alias tail; live until ev)
    u16* kh_    = (u16*)w;   w += BLH * 2;        // 8MB  (live until ev)
    u16* kcth_  = (u16*)w;   w += BLH * 2;        // 8MB  (live until wn)
    u16* Eth_   = (u16*)w;   w += BLH * 2;        // 8MB  (live until wn)
    u16* Wqh_   = (u16*)w;   w += DH * 2;
    u16* Wkh_   = (u16*)w;   w += DH * 2;
    u16* Wvh_   = (u16*)w;   w += DH * 2;
    u16* Wph_   = (u16*)w;   w += (size_t)B_ * DH * 2;
    float* lr_  = (float*)w; w += BL * 4;
    float* lwd_ = (float*)w; w += BL * 4;
    float* wd_  = (float*)w; w += BL * 4;
    float* cum_ = (float*)w; w += BL * 4;
    float* wdc_ = (float*)w; w += BL * 4;
    float* c_   = (float*)w; w += BL * 4;
    float* S_   = (float*)w; w += BL * 4;
    float* Gs_  = (float*)w; w += (size_t)B_ * NC * H_ * 4;

    u16* wp_ = Gloc_;          // alias: Gloc dead after sdot, xh dead after ev;
                               // NS*B*DH*2 = 8.4MB spans Gloc_(8MB)+xh_ head

    k_prep<<<2048, 256, 0, stream>>>(x, flrw, flrb, fwdw, fwdb, lblr, lbwd,
                                     lr_, lwd_, wd_, xh_);
    k_cumsum<<<B_ + 7 * 256, 256, 0, stream>>>(lwd_, lr_, Wq, Wk, Wv, hid,
                                               Wqh_, Wkh_, Wvh_, Wph_,
                                               cum_, wdc_, c_);
    k_mfma_qk<<<256, 512, 0, stream>>>(xh_, Wqh_, Wkh_, c_, wd_,
                                       kh_, kcth_, Gloc_);
    k_scan_carry<<<dim3(B_, 8), 64, 0, stream>>>(cum_, Gloc_, Gs_);
    k_sdot<<<2048, 256, 0, stream>>>(kh_, Gloc_, Gs_, cum_, S_);
    k_mfma_ev<<<256, 512, 0, stream>>>(kh_, xh_, Wph_, Wvh_,
                                       lr_, S_, wdc_, out, Eth_);
    k_mfma_wn<<<256, 512, 0, stream>>>(Eth_, kcth_, wp_);
    k_wnext_reduce<<<1024, 256, 0, stream>>>(hid, wp_, wdc_, out + BLH);
}

// Round 13
// 69.296 us; speedup vs baseline: 1.0617x; 1.0617x over previous
//
#include <hip/hip_runtime.h>
#include <cstdint>
#include <cstddef>

#define B_ 4
#define L_ 2048
#define D_ 512
#define H_ 512
#define CH 64            // scan chunk length (2 chunks per 128-row GEMM m-tile)
#define NC (L_ / CH)     // 32 chunks
#define NS 4             // W_next K-split (K=512 per partial)

typedef unsigned short u16;
typedef __attribute__((ext_vector_type(8))) short short8v;   // 8 bf16 (4 VGPRs)
typedef __attribute__((ext_vector_type(4))) float f32x4;

typedef __attribute__((address_space(3))) unsigned lds_uint;
typedef const __attribute__((address_space(1))) unsigned glob_uint;

__device__ __forceinline__ void glds16(const u16* g, const u16* l) {
    __builtin_amdgcn_global_load_lds((glob_uint*)g, (lds_uint*)l, 16, 0, 0);
}

// ---------- bf16 helpers ----------
__device__ __forceinline__ u16 bf16_rne(float x) {
    union { float f; unsigned u; } v; v.f = x;
    unsigned r = v.u + 0x7fffu + ((v.u >> 16) & 1u);
    return (u16)(r >> 16);
}
__device__ __forceinline__ float bf16_tof(u16 h) {
    union { unsigned u; float f; } v; v.u = ((unsigned)h) << 16;
    return v.f;
}

// ---------------- K1: rowscalars + x->bf16 ----------------
// LESSONS: r10 threadfence ~250us; r14 bulk atomics +10us; r13/r15 <2waves/SIMD
// regress; r16 carry recompute +4.4us; r17 PROBE: C0~=10.7us fixed; r18 store-
// coalescing neutral; r19 8-wave WIN; r20 BK=64 WIN; r21 3-buf/1-barrier qk+wn WIN
// (69.6 = champion); r22 ev B1-from-L2 REGRESSED +3.9us (direct global read has
// ZERO prefetch depth vs glds' 2-step cover — L2 residency is not latency cover).
// ROUND-23: clean revert to r21 champion.
__global__ __launch_bounds__(256) void k_prep(
    const float* __restrict__ x, const float* __restrict__ flr_w, const float* __restrict__ flr_b,
    const float* __restrict__ fwd_w, const float* __restrict__ fwd_b,
    const float* __restrict__ lblr, const float* __restrict__ lbwd,
    float* __restrict__ lr, float* __restrict__ lwd, float* __restrict__ wd,
    u16* __restrict__ xh)
{
    int bx = blockIdx.x;
    int wave = threadIdx.x >> 6;
    int lane = threadIdx.x & 63;
    int row  = bx * 4 + wave;                          // [0, B*L)
    const float4* xr = (const float4*)(x + (size_t)row * D_);
    const float4* wl = (const float4*)flr_w;
    const float4* ww = (const float4*)fwd_w;
    float zl = 0.f, zw = 0.f;
#pragma unroll
    for (int i = 0; i < 2; ++i) {
        int idx = lane + i * 64;
        float4 xv = xr[idx];
        float4 av = wl[idx];
        float4 bv = ww[idx];
        zl += xv.x*av.x + xv.y*av.y + xv.z*av.z + xv.w*av.w;
        zw += xv.x*bv.x + xv.y*bv.y + xv.z*bv.z + xv.w*bv.w;
        ushort4 h4;
        h4.x = bf16_rne(xv.x); h4.y = bf16_rne(xv.y);
        h4.z = bf16_rne(xv.z); h4.w = bf16_rne(xv.w);
        *(ushort4*)(xh + (size_t)row * D_ + idx * 4) = h4;
    }
#pragma unroll
    for (int off = 32; off; off >>= 1) {
        zl += __shfl_xor(zl, off, 64);
        zw += __shfl_xor(zw, off, 64);
    }
    if (lane == 0) {
        zl += flr_b[0];
        zw += fwd_b[0];
        float lrv = expf(lblr[0]) / (1.f + expf(-zl));
        float ls = (zw >= 0.f) ? (-log1pf(expf(-zw))) : (zw - log1pf(expf(zw)));  // log sigmoid
        float lw = lbwd[0] + ls;
        lr[row]  = lrv;
        lwd[row] = lw;
        wd[row]  = expf(lw);
    }
}

// ---------------- K2: per-batch prefix scan (4 blocks) + weight->bf16 (1792 blocks) ----------------
__global__ __launch_bounds__(256) void k_cumsum(
    const float* __restrict__ lwd, const float* __restrict__ lr,
    const float* __restrict__ Wq, const float* __restrict__ Wk, const float* __restrict__ Wv,
    const float* __restrict__ hid,
    u16* __restrict__ Wqh, u16* __restrict__ Wkh, u16* __restrict__ Wvh, u16* __restrict__ Wph,
    float* __restrict__ cum, float* __restrict__ wdc, float* __restrict__ c)
{
    int bx = blockIdx.x;
    if (bx >= B_) {
        int idx = bx - B_;
        int y = idx >> 8;
        const size_t DH = (size_t)D_ * H_;
        const float* s; u16* d;
        if      (y == 0) { s = Wq; d = Wqh; }
        else if (y == 1) { s = Wk; d = Wkh; }
        else if (y == 2) { s = Wv; d = Wvh; }
        else             { s = hid + (size_t)(y - 3) * DH; d = Wph + (size_t)(y - 3) * DH; }
        int i = ((idx & 255) * 256 + threadIdx.x) * 4;
        float4 v = *(const float4*)(s + i);
        ushort4 h4;
        h4.x = bf16_rne(v.x); h4.y = bf16_rne(v.y);
        h4.z = bf16_rne(v.z); h4.w = bf16_rne(v.w);
        *(ushort4*)(d + i) = h4;
        return;
    }
    int b = bx;
    int t = threadIdx.x;
    const float* in = lwd + (size_t)b * L_;
    float v[8];
    float s = 0.f;
#pragma unroll
    for (int j = 0; j < 8; ++j) { s += in[t*8 + j]; v[j] = s; }
    __shared__ float sd[256];
    __shared__ float totb;
    sd[t] = s;
    __syncthreads();
    for (int d = 1; d < 256; d <<= 1) {
        float xv = (t >= d) ? sd[t - d] : 0.f;
        __syncthreads();
        sd[t] += xv;
        __syncthreads();
    }
    float excl = sd[t] - s;
    if (t == 255) totb = sd[255];
    __syncthreads();
    float total = totb;
#pragma unroll
    for (int j = 0; j < 8; ++j) {
        int l = t*8 + j;
        float cv = excl + v[j];
        cum[(size_t)b*L_ + l] = cv;
        wdc[(size_t)b*L_ + l] = expf(cv);
        c[(size_t)b*L_ + l]   = lr[(size_t)b*L_ + l] * expf(total - cv);
    }
}

// ======= 8-wave 128x128 GEMM cores, BK=64 (512 thr, wave grid 2x4, 64x32/wave/plane) =======
// Staging: r=tid>>3, slot=tid&7 (8x16B slots/row, row stride 128B), swizzle
// slot^=(row>>1)&7 pre-applied on SOURCE (linear glds dest) and on read.
// dual-B + single: 3-buffer rotation, ONE barrier per K-step. dual-AB: 2-buf/2-barrier
// (LDS limit; r22's L2-direct B1 attempt regressed — zero prefetch depth).

__device__ __forceinline__ void gg64(int lda, int ldb, int m0, int n0,
                                     size_t& gA, size_t& gB, int& dst,
                                     int offA[2][4], int offB[2][2]) {
    const int tid = threadIdx.x;
    const int lane = tid & 63;
    const int wv = tid >> 6, wm = wv >> 2, wn = wv & 3;
    int r = tid >> 3, s = tid & 7;
    int sg = s ^ ((r >> 1) & 7);
    gA = (size_t)(m0 + r) * lda + sg * 8;
    gB = (size_t)(n0 + r) * ldb + sg * 8;
    dst = wv * 1024;                      // linear: byte = tid*16; half2 dest = +8192
#pragma unroll
    for (int ks = 0; ks < 2; ++ks) {
#pragma unroll
        for (int f = 0; f < 4; ++f) {
            int ra = wm * 64 + f * 16 + (lane & 15);
            offA[ks][f] = ra * 128 + (((ks * 4 + (lane >> 4)) ^ ((ra >> 1) & 7)) * 16);
        }
#pragma unroll
        for (int f = 0; f < 2; ++f) {
            int rb = wn * 32 + f * 16 + (lane & 15);
            offB[ks][f] = rb * 128 + (((ks * 4 + (lane >> 4)) ^ ((rb >> 1) & 7)) * 16);
        }
    }
}

// ---- dual-B (3-buf/1-barrier): acc0 = A.B0^T, acc1 = A.B1^T.
// smem: A 3x16K @0; B0 3x16K @49152; B1 3x16K @98304 (147456 total)
__device__ __forceinline__ void core8_dualB(
    char* smem, const u16* __restrict__ A_g,
    const u16* __restrict__ B0_g, const u16* __restrict__ B1_g,
    int lda, int ldb, int K, int m0, int n0, f32x4 acc0[4][2], f32x4 acc1[4][2])
{
    size_t gA, gB; int dst; int offA[2][4], offB[2][2];
    gg64(lda, ldb, m0, n0, gA, gB, dst, offA, offB);
    const size_t hA = (size_t)64 * lda, hB = (size_t)64 * ldb;
    auto stage = [&](int bi, int k0) {
        glds16(A_g  + gA + k0,      (const u16*)(smem + bi * 16384 + dst));
        glds16(A_g  + gA + hA + k0, (const u16*)(smem + bi * 16384 + 8192 + dst));
        glds16(B0_g + gB + k0,      (const u16*)(smem + 49152 + bi * 16384 + dst));
        glds16(B0_g + gB + hB + k0, (const u16*)(smem + 49152 + bi * 16384 + 8192 + dst));
        glds16(B1_g + gB + k0,      (const u16*)(smem + 98304 + bi * 16384 + dst));
        glds16(B1_g + gB + hB + k0, (const u16*)(smem + 98304 + bi * 16384 + 8192 + dst));
    };
    const int nt = K >> 6;
    stage(0, 0);
    if (nt > 1) stage(1, 64);
    int bi = 0, bs = 2;
    for (int t = 0; t < nt; ++t) {
        if (t + 1 < nt) asm volatile("s_waitcnt vmcnt(6)" ::: "memory");
        else            asm volatile("s_waitcnt vmcnt(0)" ::: "memory");
        __builtin_amdgcn_s_barrier();
        asm volatile("" ::: "memory");
        if (t + 2 < nt) stage(bs, (t + 2) << 6);
        const char* bA  = smem + bi * 16384;
        const char* bB0 = smem + 49152 + bi * 16384;
        const char* bB1 = smem + 98304 + bi * 16384;
#pragma unroll
        for (int ks = 0; ks < 2; ++ks) {
            short8v a0 = *(const short8v*)(bA + offA[ks][0]);
            short8v a1 = *(const short8v*)(bA + offA[ks][1]);
            short8v a2 = *(const short8v*)(bA + offA[ks][2]);
            short8v a3 = *(const short8v*)(bA + offA[ks][3]);
            short8v p0 = *(const short8v*)(bB0 + offB[ks][0]);
            short8v p1 = *(const short8v*)(bB0 + offB[ks][1]);
            short8v q0 = *(const short8v*)(bB1 + offB[ks][0]);
            short8v q1 = *(const short8v*)(bB1 + offB[ks][1]);
            __builtin_amdgcn_s_setprio(1);
            acc0[0][0] = __builtin_amdgcn_mfma_f32_16x16x32_bf16(a0, p0, acc0[0][0], 0, 0, 0);
            acc0[0][1] = __builtin_amdgcn_mfma_f32_16x16x32_bf16(a0, p1, acc0[0][1], 0, 0, 0);
            acc0[1][0] = __builtin_amdgcn_mfma_f32_16x16x32_bf16(a1, p0, acc0[1][0], 0, 0, 0);
            acc0[1][1] = __builtin_amdgcn_mfma_f32_16x16x32_bf16(a1, p1, acc0[1][1], 0, 0, 0);
            acc0[2][0] = __builtin_amdgcn_mfma_f32_16x16x32_bf16(a2, p0, acc0[2][0], 0, 0, 0);
            acc0[2][1] = __builtin_amdgcn_mfma_f32_16x16x32_bf16(a2, p1, acc0[2][1], 0, 0, 0);
            acc0[3][0] = __builtin_amdgcn_mfma_f32_16x16x32_bf16(a3, p0, acc0[3][0], 0, 0, 0);
            acc0[3][1] = __builtin_amdgcn_mfma_f32_16x16x32_bf16(a3, p1, acc0[3][1], 0, 0, 0);
            acc1[0][0] = __builtin_amdgcn_mfma_f32_16x16x32_bf16(a0, q0, acc1[0][0], 0, 0, 0);
            acc1[0][1] = __builtin_amdgcn_mfma_f32_16x16x32_bf16(a0, q1, acc1[0][1], 0, 0, 0);
            acc1[1][0] = __builtin_amdgcn_mfma_f32_16x16x32_bf16(a1, q0, acc1[1][0], 0, 0, 0);
            acc1[1][1] = __builtin_amdgcn_mfma_f32_16x16x32_bf16(a1, q1, acc1[1][1], 0, 0, 0);
            acc1[2][0] = __builtin_amdgcn_mfma_f32_16x16x32_bf16(a2, q0, acc1[2][0], 0, 0, 0);
            acc1[2][1] = __builtin_amdgcn_mfma_f32_16x16x32_bf16(a2, q1, acc1[2][1], 0, 0, 0);
            acc1[3][0] = __builtin_amdgcn_mfma_f32_16x16x32_bf16(a3, q0, acc1[3][0], 0, 0, 0);
            acc1[3][1] = __builtin_amdgcn_mfma_f32_16x16x32_bf16(a3, q1, acc1[3][1], 0, 0, 0);
            __builtin_amdgcn_s_setprio(0);
        }
        asm volatile("" ::: "memory");
        bi = (bi == 2) ? 0 : bi + 1;
        bs = (bs == 2) ? 0 : bs + 1;
    }
    asm volatile("" ::: "memory");
    __builtin_amdgcn_s_barrier();            // protect epilogue smem reuse
}

// ---- dual-AB (2-buf/2-barrier): acc0 = A0.B0^T, acc1 = A1.B1^T.
// smem: A0 @0; A1 @32K; B0 @64K; B1 @96K (128K)
__device__ __forceinline__ void core8_dualAB(
    char* smem, const u16* __restrict__ A0_g, const u16* __restrict__ A1_g,
    const u16* __restrict__ B0_g, const u16* __restrict__ B1_g,
    int lda, int ldb, int K, int m0, int n0, f32x4 acc0[4][2], f32x4 acc1[4][2])
{
    size_t gA, gB; int dst; int offA[2][4], offB[2][2];
    gg64(lda, ldb, m0, n0, gA, gB, dst, offA, offB);
    const size_t hA = (size_t)64 * lda, hB = (size_t)64 * ldb;
    auto stage = [&](int bi, int k0) {
        glds16(A0_g + gA + k0,      (const u16*)(smem + bi * 16384 + dst));
        glds16(A0_g + gA + hA + k0, (const u16*)(smem + bi * 16384 + 8192 + dst));
        glds16(A1_g + gA + k0,      (const u16*)(smem + 32768 + bi * 16384 + dst));
        glds16(A1_g + gA + hA + k0, (const u16*)(smem + 32768 + bi * 16384 + 8192 + dst));
        glds16(B0_g + gB + k0,      (const u16*)(smem + 65536 + bi * 16384 + dst));
        glds16(B0_g + gB + hB + k0, (const u16*)(smem + 65536 + bi * 16384 + 8192 + dst));
        glds16(B1_g + gB + k0,      (const u16*)(smem + 98304 + bi * 16384 + dst));
        glds16(B1_g + gB + hB + k0, (const u16*)(smem + 98304 + bi * 16384 + 8192 + dst));
    };
    const int nt = K >> 6;
    stage(0, 0);
    if (nt > 1) stage(1, 64);
    for (int t = 0; t < nt; ++t) {
        const int bi = t & 1;
        if (t + 1 < nt) asm volatile("s_waitcnt vmcnt(8)" ::: "memory");
        else            asm volatile("s_waitcnt vmcnt(0)" ::: "memory");
        __builtin_amdgcn_s_barrier();
        asm volatile("" ::: "memory");
        const char* bA0 = smem + bi * 16384;
        const char* bA1 = smem + 32768 + bi * 16384;
        const char* bB0 = smem + 65536 + bi * 16384;
        const char* bB1 = smem + 98304 + bi * 16384;
#pragma unroll
        for (int ks = 0; ks < 2; ++ks) {
            short8v a0 = *(const short8v*)(bA0 + offA[ks][0]);
            short8v a1 = *(const short8v*)(bA0 + offA[ks][1]);
            short8v a2 = *(const short8v*)(bA0 + offA[ks][2]);
            short8v a3 = *(const short8v*)(bA0 + offA[ks][3]);
            short8v c0 = *(const short8v*)(bA1 + offA[ks][0]);
            short8v c1 = *(const short8v*)(bA1 + offA[ks][1]);
            short8v c2 = *(const short8v*)(bA1 + offA[ks][2]);
            short8v c3 = *(const short8v*)(bA1 + offA[ks][3]);
            short8v p0 = *(const short8v*)(bB0 + offB[ks][0]);
            short8v p1 = *(const short8v*)(bB0 + offB[ks][1]);
            short8v q0 = *(const short8v*)(bB1 + offB[ks][0]);
            short8v q1 = *(const short8v*)(bB1 + offB[ks][1]);
            __builtin_amdgcn_s_setprio(1);
            acc0[0][0] = __builtin_amdgcn_mfma_f32_16x16x32_bf16(a0, p0, acc0[0][0], 0, 0, 0);
            acc0[0][1] = __builtin_amdgcn_mfma_f32_16x16x32_bf16(a0, p1, acc0[0][1], 0, 0, 0);
            acc0[1][0] = __builtin_amdgcn_mfma_f32_16x16x32_bf16(a1, p0, acc0[1][0], 0, 0, 0);
            acc0[1][1] = __builtin_amdgcn_mfma_f32_16x16x32_bf16(a1, p1, acc0[1][1], 0, 0, 0);
            acc0[2][0] = __builtin_amdgcn_mfma_f32_16x16x32_bf16(a2, p0, acc0[2][0], 0, 0, 0);
            acc0[2][1] = __builtin_amdgcn_mfma_f32_16x16x32_bf16(a2, p1, acc0[2][1], 0, 0, 0);
            acc0[3][0] = __builtin_amdgcn_mfma_f32_16x16x32_bf16(a3, p0, acc0[3][0], 0, 0, 0);
            acc0[3][1] = __builtin_amdgcn_mfma_f32_16x16x32_bf16(a3, p1, acc0[3][1], 0, 0, 0);
            acc1[0][0] = __builtin_amdgcn_mfma_f32_16x16x32_bf16(c0, q0, acc1[0][0], 0, 0, 0);
            acc1[0][1] = __builtin_amdgcn_mfma_f32_16x16x32_bf16(c0, q1, acc1[0][1], 0, 0, 0);
            acc1[1][0] = __builtin_amdgcn_mfma_f32_16x16x32_bf16(c1, q0, acc1[1][0], 0, 0, 0);
            acc1[1][1] = __builtin_amdgcn_mfma_f32_16x16x32_bf16(c1, q1, acc1[1][1], 0, 0, 0);
            acc1[2][0] = __builtin_amdgcn_mfma_f32_16x16x32_bf16(c2, q0, acc1[2][0], 0, 0, 0);
            acc1[2][1] = __builtin_amdgcn_mfma_f32_16x16x32_bf16(c2, q1, acc1[2][1], 0, 0, 0);
            acc1[3][0] = __builtin_amdgcn_mfma_f32_16x16x32_bf16(c3, q0, acc1[3][0], 0, 0, 0);
            acc1[3][1] = __builtin_amdgcn_mfma_f32_16x16x32_bf16(c3, q1, acc1[3][1], 0, 0, 0);
            __builtin_amdgcn_s_setprio(0);
        }
        asm volatile("" ::: "memory");
        __builtin_amdgcn_s_barrier();
        asm volatile("" ::: "memory");
        if (t + 2 < nt) stage(bi, (t + 2) << 6);
    }
}

// ---- single (3-buf/1-barrier): smem A 3x16K @0; B 3x16K @49152 (98304)
__device__ __forceinline__ void core8_single(
    char* smem, const u16* __restrict__ A_g, const u16* __restrict__ B_g,
    int lda, int ldb, int K, int m0, int n0, f32x4 acc[4][2])
{
    size_t gA, gB; int dst; int offA[2][4], offB[2][2];
    gg64(lda, ldb, m0, n0, gA, gB, dst, offA, offB);
    const size_t hA = (size_t)64 * lda, hB = (size_t)64 * ldb;
    auto stage = [&](int bi, int k0) {
        glds16(A_g + gA + k0,      (const u16*)(smem + bi * 16384 + dst));
        glds16(A_g + gA + hA + k0, (const u16*)(smem + bi * 16384 + 8192 + dst));
        glds16(B_g + gB + k0,      (const u16*)(smem + 49152 + bi * 16384 + dst));
        glds16(B_g + gB + hB + k0, (const u16*)(smem + 49152 + bi * 16384 + 8192 + dst));
    };
    const int nt = K >> 6;
    stage(0, 0);
    if (nt > 1) stage(1, 64);
    int bi = 0, bs = 2;
    for (int t = 0; t < nt; ++t) {
        if (t + 1 < nt) asm volatile("s_waitcnt vmcnt(4)" ::: "memory");
        else            asm volatile("s_waitcnt vmcnt(0)" ::: "memory");
        __builtin_amdgcn_s_barrier();
        asm volatile("" ::: "memory");
        if (t + 2 < nt) stage(bs, (t + 2) << 6);
        const char* bA = smem + bi * 16384;
        const char* bB = smem + 49152 + bi * 16384;
#pragma unroll
        for (int ks = 0; ks < 2; ++ks) {
            short8v a0 = *(const short8v*)(bA + offA[ks][0]);
            short8v a1 = *(const short8v*)(bA + offA[ks][1]);
            short8v a2 = *(const short8v*)(bA + offA[ks][2]);
            short8v a3 = *(const short8v*)(bA + offA[ks][3]);
            short8v p0 = *(const short8v*)(bB + offB[ks][0]);
            short8v p1 = *(const short8v*)(bB + offB[ks][1]);
            __builtin_amdgcn_s_setprio(1);
            acc[0][0] = __builtin_amdgcn_mfma_f32_16x16x32_bf16(a0, p0, acc[0][0], 0, 0, 0);
            acc[0][1] = __builtin_amdgcn_mfma_f32_16x16x32_bf16(a0, p1, acc[0][1], 0, 0, 0);
            acc[1][0] = __builtin_amdgcn_mfma_f32_16x16x32_bf16(a1, p0, acc[1][0], 0, 0, 0);
            acc[1][1] = __builtin_amdgcn_mfma_f32_16x16x32_bf16(a1, p1, acc[1][1], 0, 0, 0);
            acc[2][0] = __builtin_amdgcn_mfma_f32_16x16x32_bf16(a2, p0, acc[2][0], 0, 0, 0);
            acc[2][1] = __builtin_amdgcn_mfma_f32_16x16x32_bf16(a2, p1, acc[2][1], 0, 0, 0);
            acc[3][0] = __builtin_amdgcn_mfma_f32_16x16x32_bf16(a3, p0, acc[3][0], 0, 0, 0);
            acc[3][1] = __builtin_amdgcn_mfma_f32_16x16x32_bf16(a3, p1, acc[3][1], 0, 0, 0);
            __builtin_amdgcn_s_setprio(0);
        }
        asm volatile("" ::: "memory");
        bi = (bi == 2) ? 0 : bi + 1;
        bs = (bs == 2) ? 0 : bs + 1;
    }
    asm volatile("" ::: "memory");
    __builtin_amdgcn_s_barrier();
}

// ---------------- K3: q+k dual GEMM; scan->Gloc from q-acc; kh + (c*k)^T from k-acc ----------------
__global__ __launch_bounds__(512) void k_mfma_qk(
    const u16* __restrict__ xh,
    const u16* __restrict__ Wqh, const u16* __restrict__ Wkh,
    const float* __restrict__ cvec, const float* __restrict__ wd,
    u16* __restrict__ kh, u16* __restrict__ kcth, u16* __restrict__ Gloc)
{
    __shared__ __align__(16) char smem[147456];  // core 144K; scan reuses 32K
    __shared__ float pwd[128];
    int flat = blockIdx.x;
    flat = (flat & 7) * 32 + (flat >> 3);        // bijective XCD swizzle (nwg=256)
    int n0 = (flat & 3) * 128;
    int m0 = (flat >> 2) * 128;
    f32x4 accq[4][2], acck[4][2];
#pragma unroll
    for (int i = 0; i < 4; ++i)
#pragma unroll
    for (int j = 0; j < 2; ++j) { accq[i][j] = 0.f; acck[i][j] = 0.f; }
    core8_dualB(smem, xh, Wqh, Wkh, D_, D_, D_, m0, n0, accq, acck);

    const int lane = threadIdx.x & 63;
    const int wv = threadIdx.x >> 6, wm = wv >> 2, wn = wv & 3;
    const int colq = lane & 15, rq = lane >> 4;

    // ---- k epilogue (global only) ----
#pragma unroll
    for (int mf = 0; mf < 4; ++mf) {
        int grow0 = m0 + wm*64 + mf*16 + rq*4;
        float cv[4];
#pragma unroll
        for (int r = 0; r < 4; ++r) cv[r] = cvec[grow0 + r];
#pragma unroll
        for (int nf = 0; nf < 2; ++nf) {
            int gc = n0 + wn*32 + nf*16 + colq;
            f32x4 a = acck[mf][nf];
            ushort4 hc;
#pragma unroll
            for (int r = 0; r < 4; ++r) {
                kh[(size_t)(grow0 + r) * H_ + gc] = bf16_rne(a[r]);
                ((u16*)&hc)[r] = bf16_rne(cv[r] * a[r]);
            }
            int b = grow0 >> 11, lloc = grow0 & 2047;
            size_t tbase = (size_t)b * (H_ * L_) + (size_t)gc * L_ + lloc;
            *(ushort4*)(kcth + tbase) = hc;
        }
    }

    // ---- fused suffix scan on q-acc (2 chunks of 64 rows; tile = 128 rows) ----
    u16* g = (u16*)smem;                 // [128][128] bf16 = 32KB
#pragma unroll
    for (int mf = 0; mf < 4; ++mf) {
        int rl0 = wm*64 + mf*16 + rq*4;
#pragma unroll
        for (int nf = 0; nf < 2; ++nf) {
            int cl = wn*32 + nf*16 + colq;
#pragma unroll
            for (int r = 0; r < 4; ++r)
                g[(rl0 + r)*128 + cl] = bf16_rne(accq[mf][nf][r]);
        }
    }
    if (threadIdx.x < 128) pwd[threadIdx.x] = wd[m0 + threadIdx.x];
    __syncthreads();
    if (threadIdx.x < 256) {
        int col  = threadIdx.x & 127;
        int base = (threadIdx.x >> 7) * 64;          // chunk 0 or 1
        float G = bf16_tof(g[(base + 63)*128 + col]);
        for (int l = 62; l >= 0; --l) {
            float qv = bf16_tof(g[(base + l)*128 + col]);
            G = fmaf(pwd[base + l + 1], G, qv);
            g[(base + l)*128 + col] = bf16_rne(G);
        }
    }
    __syncthreads();
    int row = threadIdx.x >> 2, c0 = (threadIdx.x & 3) * 32;
    u16* dst = Gloc + (size_t)(m0 + row) * H_ + n0 + c0;
#pragma unroll
    for (int j = 0; j < 4; ++j)
        *(int4*)(dst + j*8) = *(const int4*)&g[row*128 + c0 + j*8];
}

// ---------------- K4: carry across NC chunks: 32 blocks, register chain ----------------
__global__ __launch_bounds__(64) void k_scan_carry(
    const float* __restrict__ cum, const u16* __restrict__ Gloc, float* __restrict__ Gs)
{
    int b = blockIdx.x;
    int h = blockIdx.y * 64 + threadIdx.x;
    __shared__ float dec[NC];
    const float* cb = cum + (size_t)b * L_;
    if (threadIdx.x < NC - 1) dec[threadIdx.x] = expf(cb[(threadIdx.x + 1) * CH] - cb[threadIdx.x * CH]);
    __syncthreads();
    const u16* g = Gloc + (size_t)b * L_ * H_ + h;
    float* gs = Gs + (size_t)b * NC * H_ + h;
    float v[NC];
#pragma unroll
    for (int c = 0; c < NC; ++c)                 // 32 independent loads in flight
        v[c] = bf16_tof(g[(size_t)(c * CH) * H_]);
    float G = v[NC - 1];
    gs[(size_t)(NC - 1) * H_] = G;
#pragma unroll
    for (int c = NC - 2; c >= 0; --c) {
        G = fmaf(dec[c], G, v[c]);
        gs[(size_t)c * H_] = G;
    }
}

// ---------------- K5: fused apply+dot: S[row] = k . (Gloc + a*Gs[c+1]) ----------------
__global__ __launch_bounds__(256) void k_sdot(
    const u16* __restrict__ kh,
    const u16* __restrict__ Gloc, const float* __restrict__ Gs,
    const float* __restrict__ cum, float* __restrict__ S)
{
    int wave = threadIdx.x >> 6, lane = threadIdx.x & 63;
    int row = blockIdx.x * 4 + wave;                 // b*L + l
    int b = row >> 11, l = row & 2047;
    int c = l / CH;
    float a = 0.f;
    const float* gsr = Gs;                           // dummy, masked by a=0
    if (c < NC - 1) {
        a = expf(cum[((size_t)b << 11) + (size_t)((c + 1) * CH)] - cum[row]);
        gsr = Gs + ((size_t)(b * NC + c + 1)) * H_;
    }
    const u16* khr = kh + (size_t)row * H_;
    const u16* glr = Gloc + (size_t)row * H_;
    const float4* gq = (const float4*)gsr;
    float s = 0.f;
    int base = lane * 8;
    ushort4 h0 = *(const ushort4*)(khr + base);
    ushort4 h1 = *(const ushort4*)(khr + base + 4);
    ushort4 g0 = *(const ushort4*)(glr + base);
    ushort4 g1 = *(const ushort4*)(glr + base + 4);
    float4 s0 = gq[lane * 2];
    float4 s1 = gq[lane * 2 + 1];
    s += bf16_tof(h0.x) * fmaf(a, s0.x, bf16_tof(g0.x));
    s += bf16_tof(h0.y) * fmaf(a, s0.y, bf16_tof(g0.y));
    s += bf16_tof(h0.z) * fmaf(a, s0.z, bf16_tof(g0.z));
    s += bf16_tof(h0.w) * fmaf(a, s0.w, bf16_tof(g0.w));
    s += bf16_tof(h1.x) * fmaf(a, s1.x, bf16_tof(g1.x));
    s += bf16_tof(h1.y) * fmaf(a, s1.y, bf16_tof(g1.y));
    s += bf16_tof(h1.z) * fmaf(a, s1.z, bf16_tof(g1.z));
    s += bf16_tof(h1.w) * fmaf(a, s1.w, bf16_tof(g1.w));
#pragma unroll
    for (int off = 32; off; off >>= 1) s += __shfl_xor(s, off, 64);
    if (lane == 0) S[row] = s;
}

// ---------------- K6: E+v dual GEMM; y + E^T epilogue (v never materialized) ----------------
__global__ __launch_bounds__(512) void k_mfma_ev(
    const u16* __restrict__ kh, const u16* __restrict__ xh,
    const u16* __restrict__ Wph, const u16* __restrict__ Wvh,
    const float* __restrict__ lr, const float* __restrict__ S, const float* __restrict__ wdc,
    float* __restrict__ y, u16* __restrict__ Eth)
{
    __shared__ __align__(16) char smem[131072];
    int flat = blockIdx.x;
    flat = (flat & 7) * 32 + (flat >> 3);        // nwg=256
    int n0 = (flat & 3) * 128;
    int m0 = ((flat >> 2) & 15) * 128;
    int b  = flat >> 6;
    f32x4 acce[4][2], accv[4][2];
#pragma unroll
    for (int i = 0; i < 4; ++i)
#pragma unroll
    for (int j = 0; j < 2; ++j) { acce[i][j] = 0.f; accv[i][j] = 0.f; }
    core8_dualAB(smem, kh + (size_t)b * L_ * H_, xh + (size_t)b * L_ * D_,
                 Wph + (size_t)b * D_ * H_, Wvh,
                 H_, H_, H_, m0, n0, acce, accv);

    const int lane = threadIdx.x & 63;
    const int wv = threadIdx.x >> 6, wm = wv >> 2, wn = wv & 3;
    const int colq = lane & 15, rq = lane >> 4;
#pragma unroll
    for (int mf = 0; mf < 4; ++mf) {
        int grow0 = m0 + wm*64 + mf*16 + rq*4;       // local l
        float ayv[4], wdv[4];
#pragma unroll
        for (int r = 0; r < 4; ++r) {
            size_t grow = (size_t)b * L_ + grow0 + r;
            ayv[r] = -lr[grow] * S[grow];
            wdv[r] = wdc[grow];
        }
#pragma unroll
        for (int nf = 0; nf < 2; ++nf) {
            int gc = n0 + wn*32 + nf*16 + colq;      // d
            f32x4 ae = acce[mf][nf];
            f32x4 av = accv[mf][nf];
            ushort4 he;
#pragma unroll
            for (int r = 0; r < 4; ++r) {
                size_t gi = ((size_t)b * L_ + grow0 + r) * D_ + gc;
                float e = ae[r] - av[r];               // E = k.Wp^T - v
                y[gi] = e * ayv[r] + ae[r] * wdv[r];   // y = E*(-lr*S) + (E+v)*wd_cross
                ((u16*)&he)[r] = bf16_rne(e);
            }
            size_t tbase = (size_t)b * (D_ * L_) + (size_t)gc * L_ + grow0;
            *(ushort4*)(Eth + tbase) = he;
        }
    }
}

// ---------------- K7: W_next inner partials via MFMA (NS-way K-split, bf16 out) ----------------
__global__ __launch_bounds__(512) void k_mfma_wn(
    const u16* __restrict__ Eth, const u16* __restrict__ kcth,
    u16* __restrict__ wp)
{
    __shared__ __align__(16) char smem[98304];
    int flat = blockIdx.x;
    flat = (flat & 7) * 32 + (flat >> 3);        // bijective XCD swizzle (nwg=256)
    int n0 = (flat & 3) * 128;
    int m0 = ((flat >> 2) & 3) * 128;
    int z  = flat >> 4;                           // [0,16)
    int b = z >> 2, s = z & 3;
    f32x4 acc[4][2];
#pragma unroll
    for (int i = 0; i < 4; ++i)
#pragma unroll
    for (int j = 0; j < 2; ++j) acc[i][j] = 0.f;
    const size_t pa = (size_t)b * (D_ * L_) + (size_t)s * (L_ / NS);
    const size_t pb = (size_t)b * (H_ * L_) + (size_t)s * (L_ / NS);
    core8_single(smem, Eth + pa, kcth + pb, L_, L_, L_ / NS, m0, n0, acc);

    u16* out = wp + (size_t)z * D_ * H_;
    const int lane = threadIdx.x & 63;
    const int wv = threadIdx.x >> 6, wm = wv >> 2, wn = wv & 3;
    const int colq = lane & 15, rq = lane >> 4;
#pragma unroll
    for (int mf = 0; mf < 4; ++mf) {
        int grow0 = m0 + wm*64 + mf*16 + rq*4;
#pragma unroll
        for (int nf = 0; nf < 2; ++nf) {
            int gc = n0 + wn*32 + nf*16 + colq;
            f32x4 a = acc[mf][nf];
#pragma unroll
            for (int r = 0; r < 4; ++r) out[(size_t)(grow0 + r) * H_ + gc] = bf16_rne(a[r]);
        }
    }
}

// ---------------- K8: W_next = wdc[L-1]*W_prev - sum_s bf16 partial ----------------
__global__ __launch_bounds__(256) void k_wnext_reduce(
    const float* __restrict__ Wp, const u16* __restrict__ wp, const float* __restrict__ wdc,
    float* __restrict__ outw)
{
    size_t g = (size_t)blockIdx.x * 256 + threadIdx.x;   // float4 over B*D*H/4
    size_t per = (size_t)D_ * H_ / 4;
    int b = (int)(g / per);
    size_t r = g % per;
    float wl = wdc[(size_t)b * L_ + (L_ - 1)];
    float4 w0 = ((const float4*)Wp)[g];
    float4 o;
    o.x = wl * w0.x; o.y = wl * w0.y; o.z = wl * w0.z; o.w = wl * w0.w;
#pragma unroll
    for (int s = 0; s < NS; ++s) {
        ushort4 p = ((const ushort4*)wp)[(size_t)(b * NS + s) * per + r];
        o.x -= bf16_tof(p.x); o.y -= bf16_tof(p.y);
        o.z -= bf16_tof(p.z); o.w -= bf16_tof(p.w);
    }
    ((float4*)outw)[g] = o;
}

extern "C" void kernel_launch(void* const* d_in, const int* in_sizes, int n_in,
                              void* d_out, int out_size, void* d_ws, size_t ws_size,
                              hipStream_t stream)
{
    (void)in_sizes; (void)n_in; (void)out_size; (void)ws_size;
    const float* x    = (const float*)d_in[0];
    const float* hid  = (const float*)d_in[1];
    const float* lblr = (const float*)d_in[2];
    const float* lbwd = (const float*)d_in[3];
    const float* Wq   = (const float*)d_in[4];
    const float* Wk   = (const float*)d_in[5];
    const float* Wv   = (const float*)d_in[6];
    const float* flrw = (const float*)d_in[7];
    const float* flrb = (const float*)d_in[8];
    const float* fwdw = (const float*)d_in[9];
    const float* fwdb = (const float*)d_in[10];
    float* out = (float*)d_out;

    const size_t BL  = (size_t)B_ * L_;        // 8192
    const size_t BLH = BL * H_;                // 4,194,304
    const size_t DH  = (size_t)D_ * H_;        // 262,144

    char* w = (char*)d_ws;
    u16* Gloc_  = (u16*)w;   w += BLH * 2;        // 8MB  (wp alias start)
    u16* xh_    = (u16*)w;   w += BLH * 2;        // 8MB  (wp alias tail; live until ev)
    u16* kh_    = (u16*)w;   w += BLH * 2;        // 8MB  (live until ev)
    u16* kcth_  = (u16*)w;   w += BLH * 2;        // 8MB  (live until wn)
    u16* Eth_   = (u16*)w;   w += BLH * 2;        // 8MB  (live until wn)
    u16* Wqh_   = (u16*)w;   w += DH * 2;
    u16* Wkh_   = (u16*)w;   w += DH * 2;
    u16* Wvh_   = (u16*)w;   w += DH * 2;
    u16* Wph_   = (u16*)w;   w += (size_t)B_ * DH * 2;
    float* lr_  = (float*)w; w += BL * 4;
    float* lwd_ = (float*)w; w += BL * 4;
    float* wd_  = (float*)w; w += BL * 4;
    float* cum_ = (float*)w; w += BL * 4;
    float* wdc_ = (float*)w; w += BL * 4;
    float* c_   = (float*)w; w += BL * 4;
    float* S_   = (float*)w; w += BL * 4;
    float* Gs_  = (float*)w; w += (size_t)B_ * NC * H_ * 4;

    u16* wp_ = Gloc_;          // alias: Gloc dead after sdot, xh dead after ev;
                               // NS*B*DH*2 = 8.4MB spans Gloc_(8MB)+xh_ head

    k_prep<<<2048, 256, 0, stream>>>(x, flrw, flrb, fwdw, fwdb, lblr, lbwd,
                                     lr_, lwd_, wd_, xh_);
    k_cumsum<<<B_ + 7 * 256, 256, 0, stream>>>(lwd_, lr_, Wq, Wk, Wv, hid,
                                               Wqh_, Wkh_, Wvh_, Wph_,
                                               cum_, wdc_, c_);
    k_mfma_qk<<<256, 512, 0, stream>>>(xh_, Wqh_, Wkh_, c_, wd_,
                                       kh_, kcth_, Gloc_);
    k_scan_carry<<<dim3(B_, 8), 64, 0, stream>>>(cum_, Gloc_, Gs_);
    k_sdot<<<2048, 256, 0, stream>>>(kh_, Gloc_, Gs_, cum_, S_);
    k_mfma_ev<<<256, 512, 0, stream>>>(kh_, xh_, Wph_, Wvh_,
                                       lr_, S_, wdc_, out, Eth_);
    k_mfma_wn<<<256, 512, 0, stream>>>(Eth_, kcth_, wp_);
    k_wnext_reduce<<<1024, 256, 0, stream>>>(hid, wp_, wdc_, out + BLH);
}